// Round 5
// baseline (1293.787 us; speedup 1.0000x reference)
//
#include <hip/hip_runtime.h>
#include <stdint.h>

typedef _Float16 f16;
typedef __attribute__((ext_vector_type(4))) float floatx4;
typedef __attribute__((ext_vector_type(8))) f16   f16x8;
typedef __attribute__((ext_vector_type(4))) f16   f16x4;

#define GLD_LDS16(gp, lp)                                                                      \
  __builtin_amdgcn_global_load_lds((const __attribute__((address_space(1))) void*)(uintptr_t)(gp), \
                                   (__attribute__((address_space(3))) void*)(uintptr_t)(lp), 16, 0, 0)

// ---------------- generalized f16 MFMA GEMM: C = alpha*A@B^T (+bias)(+resid) ----------------
struct SrlOut {
  int n0;
  const float* bias;
  const float* resid;
  float* Cf; f16* Cb;
  int ldcf, ldcb, transV;
  long long sCb, sCh;
};
struct SrlGemmArgs {
  const f16* A; const f16* B;
  int M, N, K, lda, ldb;
  long long sAb, sAh, sBb, sBh;
  float alpha;
  int nOuts;
  SrlOut out[4];
};

// --- variant 1: 256 threads, BM=128, BN=64, LDS double-buffer + register prefetch.
// Used for grid-limited 512-block GEMMs where 48KB LDS doesn't cap occupancy.
__global__ __launch_bounds__(256, 2) void srl_gemm_db(SrlGemmArgs g) {
  constexpr int BN = 64, BM = 128, BK = 64, BCH = 2, MI = 2;
  __shared__ f16 As[2][BM * BK];
  __shared__ f16 Bs[2][BN * BK];
  const int tid  = threadIdx.x;
  const int wid  = tid >> 6;
  const int lane = tid & 63;
  const int z  = blockIdx.z, zh = z & 15, zb = z >> 4;

  const int gx = gridDim.x;
  const int NT = gx * gridDim.y;
  const int L  = blockIdx.y * gx + blockIdx.x;
  const int W  = ((NT & 7) == 0) ? ((L & 7) * (NT >> 3) + (L >> 3)) : L;
  const int tn = (W % gx) * BN;
  const int tm = (W / gx) * BM;

  const f16* Ab = g.A + (long long)zb * g.sAb + (long long)zh * g.sAh + (long long)tm * g.lda;
  const f16* Bb = g.B + (long long)zb * g.sBb + (long long)zh * g.sBh + (long long)tn * g.ldb;
  const int maxAr = g.M - 1 - tm;
  const int maxBr = g.N - 1 - tn;

  int aR[4], aO[4];
#pragma unroll
  for (int i = 0; i < 4; ++i) {
    int e = wid * 2048 + i * 512 + lane * 8;
    int r = e >> 6, s = (e >> 3) & 7;
    aR[i] = r; aO[i] = ((s - r) & 7) * 8;
  }
  int bR[BCH], bO[BCH];
#pragma unroll
  for (int i = 0; i < BCH; ++i) {
    int e = wid * (BN * 16) + i * 512 + lane * 8;
    int r = e >> 6, s = (e >> 3) & 7;
    bR[i] = r; bO[i] = ((s - r) & 7) * 8;
  }

  f16x8 pa[4], pb[BCH];
  auto loadT = [&](int k0) {
#pragma unroll
    for (int i = 0; i < 4; ++i) {
      int r = aR[i] <= maxAr ? aR[i] : maxAr;
      pa[i] = *(const f16x8*)(Ab + (long long)r * g.lda + (k0 + aO[i]));
    }
#pragma unroll
    for (int i = 0; i < BCH; ++i) {
      int r = bR[i] <= maxBr ? bR[i] : maxBr;
      pb[i] = *(const f16x8*)(Bb + (long long)r * g.ldb + (k0 + bO[i]));
    }
  };
  auto storeT = [&](int buf) {
    f16* a = As[buf] + wid * 2048 + lane * 8;
    f16* b = Bs[buf] + wid * (BN * 16) + lane * 8;
#pragma unroll
    for (int i = 0; i < 4; ++i) *(f16x8*)(a + i * 512) = pa[i];
#pragma unroll
    for (int i = 0; i < BCH; ++i) *(f16x8*)(b + i * 512) = pb[i];
  };

  floatx4 acc[MI][4];
#pragma unroll
  for (int a = 0; a < MI; ++a)
#pragma unroll
    for (int b = 0; b < 4; ++b) {
      acc[a][b][0] = 0.f; acc[a][b][1] = 0.f; acc[a][b][2] = 0.f; acc[a][b][3] = 0.f;
    }

  const int wm = wid * 32;
  const int lm = lane & 15;
  const int quad = lane >> 4;

  const int T = g.K / BK;
  loadT(0);
  storeT(0);
  if (T > 1) loadT(BK);
  __syncthreads();

  for (int t = 0; t < T; ++t) {
    const int cb = t & 1;
    if (t + 1 < T) {
      storeT(cb ^ 1);
      if (t + 2 < T) loadT((t + 2) * BK);
    }
#pragma unroll
    for (int ks = 0; ks < 2; ++ks) {
      f16x8 af[MI], bfr[4];
#pragma unroll
      for (int mi = 0; mi < MI; ++mi) {
        int row = wm + mi * 16 + lm;
        int sg = ((ks * 4 + quad) + row) & 7;
        af[mi] = *(const f16x8*)(As[cb] + row * 64 + sg * 8);
      }
#pragma unroll
      for (int ni = 0; ni < 4; ++ni) {
        int row = ni * 16 + lm;
        int sg = ((ks * 4 + quad) + row) & 7;
        bfr[ni] = *(const f16x8*)(Bs[cb] + row * 64 + sg * 8);
      }
#pragma unroll
      for (int mi = 0; mi < MI; ++mi)
#pragma unroll
        for (int ni = 0; ni < 4; ++ni)
          acc[mi][ni] = __builtin_amdgcn_mfma_f32_16x16x32_f16(af[mi], bfr[ni], acc[mi][ni], 0, 0, 0);
    }
    __syncthreads();
  }

  int oi = 0;
  for (int j = 1; j < g.nOuts; ++j)
    if (tn >= g.out[j].n0) oi = j;
  const SrlOut O = g.out[oi];
  const long long zc = (long long)zb * O.sCb + (long long)zh * O.sCh;
#pragma unroll
  for (int mi = 0; mi < MI; ++mi) {
#pragma unroll
    for (int r = 0; r < 4; ++r) {
      int m = tm + wm + mi * 16 + quad * 4 + r;
      if (m >= g.M) continue;
#pragma unroll
      for (int ni = 0; ni < 4; ++ni) {
        int n = tn + ni * 16 + lm;
        if (n >= g.N) continue;
        int nl = n - O.n0;
        float v = acc[mi][ni][r] * g.alpha;
        if (O.bias)  v += O.bias[nl];
        if (O.resid) v += O.resid[(long long)m * O.ldcf + nl];
        if (O.Cf)    O.Cf[zc + (long long)m * O.ldcf + nl] = v;
        if (O.Cb) {
          long long idx = O.transV
              ? ((long long)(m >> 10) * 1048576 + (long long)nl * 1024 + (m & 1023))
              : (zc + (long long)m * O.ldcb + nl);
          O.Cb[idx] = (f16)v;
        }
      }
    }
  }
}

// --- variant 2: 128 threads / 2 waves, BM=128, BN=64, single-buffer global_load_lds.
// 24KB LDS -> 6 blocks/CU; big grids (1792 for QKVR) give many INDEPENDENT barriers per CU.
__global__ __launch_bounds__(128, 2) void srl_gemm2(SrlGemmArgs g) {
  constexpr int BK = 64;
  __shared__ f16 As[128 * BK];
  __shared__ f16 Bs[64 * BK];
  const int tid  = threadIdx.x;
  const int wid  = tid >> 6;
  const int lane = tid & 63;
  const int z  = blockIdx.z, zh = z & 15, zb = z >> 4;

  const int gx = gridDim.x;
  const int NT = gx * gridDim.y;
  const int L  = blockIdx.y * gx + blockIdx.x;
  const int W  = ((NT & 7) == 0) ? ((L & 7) * (NT >> 3) + (L >> 3)) : L;
  const int tn = (W % gx) * 64;
  const int tm = (W / gx) * 128;

  const f16* Ab = g.A + (long long)zb * g.sAb + (long long)zh * g.sAh + (long long)tm * g.lda;
  const f16* Bb = g.B + (long long)zb * g.sBb + (long long)zh * g.sBh + (long long)tn * g.ldb;
  const int maxAr = g.M - 1 - tm;
  const int maxBr = g.N - 1 - tn;

  // A: 8192 elems, 4096/wave = 8 chunks; B: 4096 elems, 2048/wave = 4 chunks
  int aR[8], aO[8];
#pragma unroll
  for (int i = 0; i < 8; ++i) {
    int e = wid * 4096 + i * 512 + lane * 8;
    int r = e >> 6, s = (e >> 3) & 7;
    aR[i] = r; aO[i] = ((s - r) & 7) * 8;
  }
  int bR[4], bO[4];
#pragma unroll
  for (int i = 0; i < 4; ++i) {
    int e = wid * 2048 + i * 512 + lane * 8;
    int r = e >> 6, s = (e >> 3) & 7;
    bR[i] = r; bO[i] = ((s - r) & 7) * 8;
  }
  f16* lA = As + wid * 4096;
  f16* lB = Bs + wid * 2048;

  floatx4 acc[4][4];
#pragma unroll
  for (int a = 0; a < 4; ++a)
#pragma unroll
    for (int b = 0; b < 4; ++b) {
      acc[a][b][0] = 0.f; acc[a][b][1] = 0.f; acc[a][b][2] = 0.f; acc[a][b][3] = 0.f;
    }

  const int wm = wid * 64;
  const int lm = lane & 15;
  const int quad = lane >> 4;

  for (int k0 = 0; k0 < g.K; k0 += BK) {
    __syncthreads();
#pragma unroll
    for (int i = 0; i < 8; ++i) {
      int r = aR[i] <= maxAr ? aR[i] : maxAr;
      GLD_LDS16(Ab + (long long)r * g.lda + (k0 + aO[i]), lA + i * 512);
    }
#pragma unroll
    for (int i = 0; i < 4; ++i) {
      int r = bR[i] <= maxBr ? bR[i] : maxBr;
      GLD_LDS16(Bb + (long long)r * g.ldb + (k0 + bO[i]), lB + i * 512);
    }
    __syncthreads();
#pragma unroll
    for (int ks = 0; ks < 2; ++ks) {
      f16x8 af[4], bfr[4];
#pragma unroll
      for (int mi = 0; mi < 4; ++mi) {
        int row = wm + mi * 16 + lm;
        int sg = ((ks * 4 + quad) + row) & 7;
        af[mi] = *(const f16x8*)(As + row * 64 + sg * 8);
      }
#pragma unroll
      for (int ni = 0; ni < 4; ++ni) {
        int row = ni * 16 + lm;
        int sg = ((ks * 4 + quad) + row) & 7;
        bfr[ni] = *(const f16x8*)(Bs + row * 64 + sg * 8);
      }
#pragma unroll
      for (int mi = 0; mi < 4; ++mi)
#pragma unroll
        for (int ni = 0; ni < 4; ++ni)
          acc[mi][ni] = __builtin_amdgcn_mfma_f32_16x16x32_f16(af[mi], bfr[ni], acc[mi][ni], 0, 0, 0);
    }
  }

  int oi = 0;
  for (int j = 1; j < g.nOuts; ++j)
    if (tn >= g.out[j].n0) oi = j;
  const SrlOut O = g.out[oi];
  const long long zc = (long long)zb * O.sCb + (long long)zh * O.sCh;
#pragma unroll
  for (int mi = 0; mi < 4; ++mi) {
#pragma unroll
    for (int r = 0; r < 4; ++r) {
      int m = tm + wm + mi * 16 + quad * 4 + r;
      if (m >= g.M) continue;
#pragma unroll
      for (int ni = 0; ni < 4; ++ni) {
        int n = tn + ni * 16 + lm;
        if (n >= g.N) continue;
        int nl = n - O.n0;
        float v = acc[mi][ni][r] * g.alpha;
        if (O.bias)  v += O.bias[nl];
        if (O.resid) v += O.resid[(long long)m * O.ldcf + nl];
        if (O.Cf)    O.Cf[zc + (long long)m * O.ldcf + nl] = v;
        if (O.Cb) {
          long long idx = O.transV
              ? ((long long)(m >> 10) * 1048576 + (long long)nl * 1024 + (m & 1023))
              : (zc + (long long)m * O.ldcb + nl);
          O.Cb[idx] = (f16)v;
        }
      }
    }
  }
}

// ---------------- fused flash attention ----------------
struct SrlFlashArgs {
  const f16* Q; const f16* K; const f16* VT; f16* O;
  long long sQb, sKb, sVb;
  float scale;   // includes log2(e)
};

__global__ __launch_bounds__(256, 2) void srl_flash(SrlFlashArgs a) {
  __shared__ f16 Qs[8192];
  __shared__ f16 Ks[8192];
  __shared__ f16 VTs[8192];
  __shared__ f16 Ps[4][4096];
  const int tid = threadIdx.x, wid = tid >> 6, lane = tid & 63;
  const int quad = lane >> 4, c = lane & 15;
  const int L = blockIdx.x;
  const int bh = (L & 7) + ((L >> 6) << 3);
  const int qt = (L >> 3) & 7;
  const int b = bh >> 4, h = bh & 15;
  const f16* Qg = a.Q + (long long)b * a.sQb + (long long)qt * 131072 + h * 64;
  const f16* Kg = a.K + (long long)b * a.sKb + h * 64;
  const f16* Vg = a.VT + (long long)b * a.sVb + (long long)h * 65536;
  f16* Og = a.O + (long long)b * 1048576 + (long long)qt * 131072 + h * 64;

  int rRow[4], rOff[4];
#pragma unroll
  for (int i = 0; i < 4; ++i) {
    int e = wid * 2048 + i * 512 + lane * 8;
    int r = e >> 6, gL = (e >> 3) & 7;
    rRow[i] = r; rOff[i] = ((gL - r) & 7) * 8;
  }
  int vRow[4], vOff[4];
#pragma unroll
  for (int i = 0; i < 4; ++i) {
    int e = wid * 2048 + i * 512 + lane * 8;
    int d = e >> 7, gL = (e >> 3) & 15;
    vRow[i] = d; vOff[i] = ((gL - (d & 7)) & 15) * 8;
  }

#pragma unroll
  for (int i = 0; i < 4; ++i)
    GLD_LDS16(Qg + (long long)rRow[i] * 1024 + rOff[i], Qs + wid * 2048 + i * 512);
  __syncthreads();

  const int wq = wid * 32;
  f16x8 qf[2][2];
#pragma unroll
  for (int nf = 0; nf < 2; ++nf)
#pragma unroll
    for (int ch = 0; ch < 2; ++ch) {
      int row = wq + nf * 16 + c;
      int slot = ((ch * 4 + quad) + row) & 7;
      f16x8 v = *(const f16x8*)(Qs + row * 64 + slot * 8);
      f16 sc = (f16)a.scale;
#pragma unroll
      for (int j = 0; j < 8; ++j) v[j] = v[j] * sc;
      qf[nf][ch] = v;
    }

  float l_s[2] = {0.f, 0.f};
  floatx4 Oa[2][4];
#pragma unroll
  for (int nf = 0; nf < 2; ++nf)
#pragma unroll
    for (int no = 0; no < 4; ++no) {
      Oa[nf][no][0] = 0.f; Oa[nf][no][1] = 0.f; Oa[nf][no][2] = 0.f; Oa[nf][no][3] = 0.f;
    }

  for (int t = 0; t < 8; ++t) {
    __syncthreads();
#pragma unroll
    for (int i = 0; i < 4; ++i)
      GLD_LDS16(Kg + (long long)(t * 128 + rRow[i]) * 1024 + rOff[i], Ks + wid * 2048 + i * 512);
#pragma unroll
    for (int i = 0; i < 4; ++i)
      GLD_LDS16(Vg + (long long)vRow[i] * 1024 + (t * 128 + vOff[i]), VTs + wid * 2048 + i * 512);
    __syncthreads();

    floatx4 sT[2][8];
#pragma unroll
    for (int nf = 0; nf < 2; ++nf)
#pragma unroll
      for (int mf = 0; mf < 8; ++mf) {
        sT[nf][mf][0] = 0.f; sT[nf][mf][1] = 0.f; sT[nf][mf][2] = 0.f; sT[nf][mf][3] = 0.f;
      }
#pragma unroll
    for (int ch = 0; ch < 2; ++ch)
#pragma unroll
      for (int mf = 0; mf < 8; ++mf) {
        int key = mf * 16 + c;
        int slot = ((ch * 4 + quad) + key) & 7;
        f16x8 kf = *(const f16x8*)(Ks + key * 64 + slot * 8);
        sT[0][mf] = __builtin_amdgcn_mfma_f32_16x16x32_f16(kf, qf[0][ch], sT[0][mf], 0, 0, 0);
        sT[1][mf] = __builtin_amdgcn_mfma_f32_16x16x32_f16(kf, qf[1][ch], sT[1][mf], 0, 0, 0);
      }

#pragma unroll
    for (int nf = 0; nf < 2; ++nf) {
      float lt = 0.f;
      const int q = nf * 16 + c;
#pragma unroll
      for (int mf = 0; mf < 8; ++mf) {
        f16x4 pk;
#pragma unroll
        for (int r = 0; r < 4; ++r) {
          float p = __builtin_amdgcn_exp2f(sT[nf][mf][r]);
          lt += p;
          pk[r] = (f16)p;
        }
        int kg = mf * 2 + (quad >> 1), sub = (quad & 1) * 4;
        int slot = (kg + (q & 7)) & 15;
        *(f16x4*)(Ps[wid] + q * 128 + slot * 8 + sub) = pk;
      }
      lt += __shfl_xor(lt, 16);
      lt += __shfl_xor(lt, 32);
      l_s[nf] += lt;
    }
#pragma unroll
    for (int cc = 0; cc < 4; ++cc) {
      f16x8 af[2];
#pragma unroll
      for (int nf = 0; nf < 2; ++nf) {
        int q = nf * 16 + c;
        int slot = ((cc * 4 + quad) + (q & 7)) & 15;
        af[nf] = *(const f16x8*)(Ps[wid] + q * 128 + slot * 8);
      }
#pragma unroll
      for (int no = 0; no < 4; ++no) {
        int d = no * 16 + c;
        int slot = ((cc * 4 + quad) + (d & 7)) & 15;
        f16x8 vf = *(const f16x8*)(VTs + d * 128 + slot * 8);
        Oa[0][no] = __builtin_amdgcn_mfma_f32_16x16x32_f16(af[0], vf, Oa[0][no], 0, 0, 0);
        Oa[1][no] = __builtin_amdgcn_mfma_f32_16x16x32_f16(af[1], vf, Oa[1][no], 0, 0, 0);
      }
    }
  }

#pragma unroll
  for (int nf = 0; nf < 2; ++nf)
#pragma unroll
    for (int r = 0; r < 4; ++r) {
      float li = 1.f / __shfl(l_s[nf], quad * 4 + r);
      int qrow = wq + nf * 16 + quad * 4 + r;
#pragma unroll
      for (int no = 0; no < 4; ++no)
        Qs[qrow * 64 + no * 16 + c] = (f16)(Oa[nf][no][r] * li);
    }
  __syncthreads();
#pragma unroll
  for (int i = 0; i < 4; ++i) {
    int e = wid * 2048 + i * 512 + lane * 8;
    int row = e >> 6, col = e & 63;
    *(f16x8*)(Og + (long long)row * 1024 + col) = *(const f16x8*)(Qs + e);
  }
}

// ---------------- rule softmax ----------------
__global__ __launch_bounds__(256) void srl_softmax_rule(const float* logits, f16* probs) {
  __shared__ float red[16];
  const long long row = blockIdx.x;
  const float* p = logits + row * 512;
  const int tid = threadIdx.x;
  float v0 = p[tid], v1 = p[tid + 256];
  float mx = fmaxf(v0, v1);
#pragma unroll
  for (int o = 32; o > 0; o >>= 1) mx = fmaxf(mx, __shfl_down(mx, o));
  const int wid = tid >> 6, lane = tid & 63;
  if (lane == 0) red[wid] = mx;
  __syncthreads();
  if (tid == 0) red[8] = fmaxf(fmaxf(red[0], red[1]), fmaxf(red[2], red[3]));
  __syncthreads();
  mx = red[8];
  float e0 = __expf(v0 - mx), e1 = __expf(v1 - mx);
  float s = e0 + e1;
#pragma unroll
  for (int o = 32; o > 0; o >>= 1) s += __shfl_down(s, o);
  if (lane == 0) red[wid + 4] = s;
  __syncthreads();
  if (tid == 0) red[9] = 1.f / (red[4] + red[5] + red[6] + red[7]);
  __syncthreads();
  const float inv = red[9];
  probs[row * 512 + tid] = (f16)(e0 * inv);
  probs[row * 512 + tid + 256] = (f16)(e1 * inv);
}

// ---------------- LayerNorm + exact GELU over sum of two split-K partials + bias ------------
__global__ __launch_bounds__(256) void srl_ln_gelu2(const float* x0, const float* x1,
                                                    const float* b1,
                                                    const float* gam, const float* bet, f16* out) {
  __shared__ float red[16];
  const long long row = blockIdx.x;
  const int tid = threadIdx.x;
  float4 a0 = *(const float4*)(x0 + row * 1024 + tid * 4);
  float4 a1 = *(const float4*)(x1 + row * 1024 + tid * 4);
  float4 bb = *(const float4*)(b1 + tid * 4);
  float v[4] = {a0.x + a1.x + bb.x, a0.y + a1.y + bb.y, a0.z + a1.z + bb.z, a0.w + a1.w + bb.w};
  float s = v[0] + v[1] + v[2] + v[3];
  float s2 = v[0] * v[0] + v[1] * v[1] + v[2] * v[2] + v[3] * v[3];
#pragma unroll
  for (int o = 32; o > 0; o >>= 1) { s += __shfl_down(s, o); s2 += __shfl_down(s2, o); }
  const int wid = tid >> 6, lane = tid & 63;
  if (lane == 0) { red[wid] = s; red[wid + 4] = s2; }
  __syncthreads();
  if (tid == 0) {
    float ts = red[0] + red[1] + red[2] + red[3];
    float ts2 = red[4] + red[5] + red[6] + red[7];
    float mu = ts * (1.f / 1024.f);
    float var = ts2 * (1.f / 1024.f) - mu * mu;
    red[8] = mu;
    red[9] = rsqrtf(var + 1e-5f);
  }
  __syncthreads();
  const float mu = red[8], rstd = red[9];
  f16x4 o4;
#pragma unroll
  for (int i = 0; i < 4; ++i) {
    int c = tid * 4 + i;
    float t = (v[i] - mu) * rstd * gam[c] + bet[c];
    float ge = 0.5f * t * (1.f + erff(t * 0.70710678118654752f));
    o4[i] = (f16)ge;
  }
  *(f16x4*)(out + row * 1024 + tid * 4) = o4;
}

// ---------------- batched weight convert (+optional transpose) fp32 -> f16 ----------------
struct SrlTcEnt { const float* src; f16* dst; int rows, cols, trans, tileStart; };
struct SrlTcArgs { SrlTcEnt e[16]; };

__global__ __launch_bounds__(256) void srl_convert_weights(SrlTcArgs a) {
  __shared__ float t[32][33];
  const int bt = blockIdx.x;
  int ei = 0;
#pragma unroll
  for (int j = 1; j < 16; ++j)
    if (bt >= a.e[j].tileStart) ei = j;
  SrlTcEnt E = a.e[ei];
  const int lt = bt - E.tileStart;
  const int tcols = E.cols >> 5;
  const int tr = lt / tcols;
  const int tc = lt - tr * tcols;
  const int r = threadIdx.x >> 5;
  const int c = threadIdx.x & 31;
  if (!E.trans) {
#pragma unroll
    for (int p = 0; p < 4; ++p) {
      long long rr = tr * 32 + r + p * 8;
      long long idx = rr * E.cols + tc * 32 + c;
      E.dst[idx] = (f16)E.src[idx];
    }
  } else {
#pragma unroll
    for (int p = 0; p < 4; ++p)
      t[r + p * 8][c] = E.src[(long long)(tr * 32 + r + p * 8) * E.cols + tc * 32 + c];
    __syncthreads();
#pragma unroll
    for (int p = 0; p < 4; ++p)
      E.dst[(long long)(tc * 32 + r + p * 8) * E.rows + tr * 32 + c] = (f16)t[c][r + p * 8];
  }
}

// ---------------- fused bias prep ----------------
__global__ __launch_bounds__(256) void srl_prep_bias(const float* rsel_b, const float* bq,
                                                     const float* bk, const float* bv,
                                                     const float* bmq, const float* maq_w,
                                                     const float* bmaq,
                                                     float* bias_qkvr, float* bcomp) {
  int i = blockIdx.x * 256 + threadIdx.x;
  if (i < 3584) {
    float v;
    if (i < 512) v = rsel_b[i];
    else if (i < 1536) v = bq[i - 512];
    else if (i < 2560) v = bk[i - 1536];
    else v = bv[i - 2560];
    bias_qkvr[i] = v;
  } else if (i < 3584 + 1024) {
    int m = i - 3584;
    float s = bmaq[m];
    for (int t = 0; t < 1024; ++t) s += bmq[t] * maq_w[(long long)t * 1024 + m];
    bcomp[m] = s;
  }
}

// ---------------- h init / finalize ----------------
__global__ __launch_bounds__(256) void srl_h_init(const float* hidden, float* hf, f16* hx) {
  long long base = ((long long)blockIdx.x * 256 + threadIdx.x) * 4;
  float4 v = *(const float4*)(hidden + base);
  *(float4*)(hf + base) = v;
  long long row = base >> 10;
  int col = (int)(base & 1023);
  f16x4 b;
  b[0] = (f16)v.x; b[1] = (f16)v.y; b[2] = (f16)v.z; b[3] = (f16)v.w;
  *(f16x4*)(hx + row * 2048 + col) = b;
}

__global__ __launch_bounds__(256) void srl_finalize(const float* hf, const float* w, const float* b,
                                                    float* out, float* conf) {
  const int bid = blockIdx.x;
  if (bid < 4096) {
    long long base = ((long long)bid * 256 + threadIdx.x) * 4;
    *(float4*)(out + base) = *(const float4*)(hf + base);
  } else {
    const int row = (bid - 4096) * 4 + (threadIdx.x >> 6);
    const int lane = threadIdx.x & 63;
    const float* p = hf + (long long)row * 1024;
    float s = 0.f;
    for (int j = lane; j < 1024; j += 64) s += p[j] * w[j];
#pragma unroll
    for (int o = 32; o > 0; o >>= 1) s += __shfl_down(s, o);
    if (lane == 0) conf[row] = 1.f / (1.f + __expf(-(s + b[0])));
  }
}

// =====================================================================================
extern "C" void kernel_launch(void* const* d_in, const int* in_sizes, int n_in,
                              void* d_out, int out_size, void* d_ws, size_t ws_size,
                              hipStream_t stream) {
  (void)in_sizes; (void)n_in; (void)out_size; (void)ws_size;
  const float* in_hidden   = (const float*)d_in[0];
  const float* in_rule_emb = (const float*)d_in[1];
  const float* in_rsel_w   = (const float*)d_in[2];
  const float* in_rsel_b   = (const float*)d_in[3];
  const float* in_attn_wq  = (const float*)d_in[4];
  const float* in_attn_bq  = (const float*)d_in[5];
  const float* in_attn_wk  = (const float*)d_in[6];
  const float* in_attn_bk  = (const float*)d_in[7];
  const float* in_attn_wv  = (const float*)d_in[8];
  const float* in_attn_bv  = (const float*)d_in[9];
  const float* in_attn_wo  = (const float*)d_in[10];
  const float* in_attn_bo  = (const float*)d_in[11];
  const float* in_memory   = (const float*)d_in[12];
  const float* in_mq_w     = (const float*)d_in[13];
  const float* in_mq_b     = (const float*)d_in[14];
  const float* in_mk_w     = (const float*)d_in[15];
  const float* in_mk_b     = (const float*)d_in[16];
  const float* in_mv_w     = (const float*)d_in[17];
  const float* in_mv_b     = (const float*)d_in[18];
  const float* in_maq_w    = (const float*)d_in[19];
  const float* in_maq_b    = (const float*)d_in[20];
  const float* in_mak_w    = (const float*)d_in[21];
  const float* in_mak_b    = (const float*)d_in[22];
  const float* in_mav_w    = (const float*)d_in[23];
  const float* in_mav_b    = (const float*)d_in[24];
  const float* in_mao_w    = (const float*)d_in[25];
  const float* in_mao_b    = (const float*)d_in[26];
  const float* in_ra_w1    = (const float*)d_in[27];
  const float* in_ra_b1    = (const float*)d_in[28];
  const float* in_ln_s     = (const float*)d_in[29];
  const float* in_ln_b     = (const float*)d_in[30];
  const float* in_ra_w2    = (const float*)d_in[31];
  const float* in_ra_b2    = (const float*)d_in[32];
  const float* in_conf_w   = (const float*)d_in[33];
  const float* in_conf_b   = (const float*)d_in[34];

  char* ws = (char*)d_ws;
  size_t off = 0;
  auto alloc = [&](size_t bytes) -> void* {
    void* p = ws + off;
    off = (off + bytes + 255) & ~(size_t)255;
    return p;
  };
  f16* wt_qkvr    = (f16*)alloc(3584 * 1024 * 2);
  float* bias_qkvr= (float*)alloc(3584 * 4);
  f16* wt_attn_o  = (f16*)alloc(1048576 * 2);
  f16* wt_mq_comp = (f16*)alloc(1048576 * 2);
  float* bcomp    = (float*)alloc(1024 * 4);
  f16* wt_mattn_o = (f16*)alloc(1048576 * 2);
  f16* wt_ra1     = (f16*)alloc(2097152 * 2);
  f16* wt_ra2     = (f16*)alloc(1048576 * 2);
  f16* wt_remb    = (f16*)alloc(524288 * 2);
  f16* wt_mem_kv  = (f16*)alloc(2097152 * 2);
  f16* wt_mattn_k = (f16*)alloc(1048576 * 2);
  f16* wt_mattn_v = (f16*)alloc(1048576 * 2);
  f16* mem_h      = (f16*)alloc(1048576 * 2);
  f16* mk_h       = (f16*)alloc(1048576 * 2);
  f16* mv_h       = (f16*)alloc(1048576 * 2);
  f16* mak_h      = (f16*)alloc(1048576 * 2);
  f16* mavT_h     = (f16*)alloc(1048576 * 2);
  float* h_f      = (float*)alloc(4194304 * 4);
  f16* hx         = (f16*)alloc(8388608 * 2);
  f16* q_h        = (f16*)alloc(4194304 * 2);
  f16* k_h        = (f16*)alloc(4194304 * 2);
  f16* vT_h       = (f16*)alloc(4194304 * 2);
  f16* ctx_h      = (f16*)alloc(4194304 * 2);
  f16* u_h        = (f16*)alloc(4194304 * 2);
  char* arena     = (char*)alloc(33554432);
  float* logits_f = (float*)arena;                  // [4096,512] fp32 (consumed before ra1 writes)
  f16* probs_h    = (f16*)(arena + 8388608);        // consumed by remb before ra1
  float* ra1_p0   = (float*)arena;                  // split-K partial 0 [4096,1024] fp32
  float* ra1_p1   = (float*)(arena + 16777216);     // split-K partial 1
  f16* mqw_nt     = (f16*)arena;                    // preamble only
  f16* wmaq_t     = (f16*)(arena + 2097152);        // preamble only

  auto mkOut = [](int n0, const float* bias, const float* resid, float* Cf, int ldcf,
                  f16* Cb, int ldcb, int transV, long long sCb, long long sCh) {
    SrlOut o;
    o.n0 = n0; o.bias = bias; o.resid = resid; o.Cf = Cf; o.Cb = Cb;
    o.ldcf = ldcf; o.ldcb = ldcb; o.transV = transV; o.sCb = sCb; o.sCh = sCh;
    return o;
  };
  // dbuf 4-wave kernel (BN=64) for grid-limited GEMMs
  auto runDb = [&](int M, int N, int K, const f16* A, int lda, const f16* B, int ldb,
                   float alpha, int Z, long long sAb, long long sAh, long long sBb, long long sBh,
                   SrlGemmArgs g) {
    g.A = A; g.B = B; g.M = M; g.N = N; g.K = K; g.lda = lda; g.ldb = ldb;
    g.sAb = sAb; g.sAh = sAh; g.sBb = sBb; g.sBh = sBh; g.alpha = alpha;
    dim3 grid((N + 63) / 64, (M + 127) / 128, Z);
    hipLaunchKernelGGL(srl_gemm_db, grid, dim3(256), 0, stream, g);
  };
  auto runDb1 = [&](int M, int N, int K, const f16* A, int lda, const f16* B, int ldb,
                    float alpha, const float* bias, const float* resid, float* Cf, int ldcf,
                    f16* Cb, int ldcb, int transV) {
    SrlGemmArgs g{};
    g.nOuts = 1;
    g.out[0] = mkOut(0, bias, resid, Cf, ldcf, Cb, ldcb, transV, 0, 0);
    runDb(M, N, K, A, lda, B, ldb, alpha, 1, 0, 0, 0, 0, g);
  };
  // 2-wave GLD kernel for the big-grid QKVR
  auto runW2 = [&](int M, int N, int K, const f16* A, int lda, const f16* B, int ldb,
                   float alpha, SrlGemmArgs g) {
    g.A = A; g.B = B; g.M = M; g.N = N; g.K = K; g.lda = lda; g.ldb = ldb;
    g.sAb = 0; g.sAh = 0; g.sBb = 0; g.sBh = 0; g.alpha = alpha;
    dim3 grid((N + 63) / 64, (M + 127) / 128, 1);
    hipLaunchKernelGGL(srl_gemm2, grid, dim3(128), 0, stream, g);
  };

  // ---- one-time weight convert/transpose ----
  SrlTcArgs tc;
  int ts = 0;
  auto setent = [&](int i, const float* s, f16* d, int rows, int cols, int trans) {
    tc.e[i].src = s; tc.e[i].dst = d; tc.e[i].rows = rows; tc.e[i].cols = cols;
    tc.e[i].trans = trans; tc.e[i].tileStart = ts;
    ts += (rows / 32) * (cols / 32);
  };
  setent(0,  in_attn_wq, wt_qkvr + 512 * 1024, 1024, 1024, 1);
  setent(1,  in_attn_wk, wt_qkvr + 1536 * 1024, 1024, 1024, 1);
  setent(2,  in_attn_wv, wt_qkvr + 2560 * 1024, 1024, 1024, 1);
  setent(3,  in_rsel_w,  wt_qkvr, 1024, 512, 1);
  setent(4,  in_attn_wo, wt_attn_o, 1024, 1024, 1);
  setent(5,  in_mq_w,    mqw_nt, 1024, 1024, 0);
  setent(6,  in_maq_w,   wmaq_t, 1024, 1024, 1);
  setent(7,  in_mak_w,   wt_mattn_k, 1024, 1024, 1);
  setent(8,  in_mav_w,   wt_mattn_v, 1024, 1024, 1);
  setent(9,  in_mk_w,    wt_mem_kv, 1024, 1024, 1);
  setent(10, in_mv_w,    wt_mem_kv + 1048576, 1024, 1024, 1);
  setent(11, in_mao_w,   wt_mattn_o, 1024, 1024, 1);
  setent(12, in_ra_w1,   wt_ra1, 2048, 1024, 1);
  setent(13, in_ra_w2,   wt_ra2, 1024, 1024, 1);
  setent(14, in_rule_emb, wt_remb, 512, 1024, 1);
  setent(15, in_memory,  mem_h, 1024, 1024, 0);
  hipLaunchKernelGGL(srl_convert_weights, dim3(ts), dim3(256), 0, stream, tc);
  hipLaunchKernelGGL(srl_prep_bias, dim3(18), dim3(256), 0, stream,
                     in_rsel_b, in_attn_bq, in_attn_bk, in_attn_bv,
                     in_mq_b, in_maq_w, in_maq_b, bias_qkvr, bcomp);
  hipLaunchKernelGGL(srl_h_init, dim3(4096), dim3(256), 0, stream, in_hidden, h_f, hx);

  // ---- preamble GEMMs ----
  {
    SrlGemmArgs g{};
    g.nOuts = 2;
    g.out[0] = mkOut(0, in_mk_b, nullptr, nullptr, 0, mk_h, 1024, 0, 0, 0);
    g.out[1] = mkOut(1024, in_mv_b, nullptr, nullptr, 0, mv_h, 1024, 0, 0, 0);
    runDb(1024, 2048, 1024, mem_h, 1024, wt_mem_kv, 1024, 1.f, 1, 0, 0, 0, 0, g);
  }
  runDb1(1024, 1024, 1024, mk_h, 1024, wt_mattn_k, 1024, 1.f, in_mak_b, nullptr, nullptr, 0, mak_h, 1024, 0);
  runDb1(1024, 1024, 1024, mv_h, 1024, wt_mattn_v, 1024, 1.f, in_mav_b, nullptr, nullptr, 0, mavT_h, 0, 1);
  runDb1(1024, 1024, 1024, wmaq_t, 1024, mqw_nt, 1024, 1.f, nullptr, nullptr, nullptr, 0, wt_mq_comp, 1024, 0);

  const float kLog2e = 1.4426950408889634f;
  for (int step = 0; step < 3; ++step) {
    {  // fused rule-logits + Q + K + V projection, 2-wave kernel, 1792-block grid
      SrlGemmArgs g{};
      g.nOuts = 4;
      g.out[0] = mkOut(0,    bias_qkvr,        nullptr, logits_f, 512, nullptr, 0, 0, 0, 0);
      g.out[1] = mkOut(512,  bias_qkvr + 512,  nullptr, nullptr, 0, q_h, 1024, 0, 0, 0);
      g.out[2] = mkOut(1536, bias_qkvr + 1536, nullptr, nullptr, 0, k_h, 1024, 0, 0, 0);
      g.out[3] = mkOut(2560, bias_qkvr + 2560, nullptr, nullptr, 0, vT_h, 0, 1, 0, 0);
      runW2(4096, 3584, 1024, hx, 2048, wt_qkvr, 1024, 1.f, g);
    }
    hipLaunchKernelGGL(srl_softmax_rule, dim3(4096), dim3(256), 0, stream, logits_f, probs_h);
    runDb1(4096, 1024, 512, probs_h, 512, wt_remb, 512, 1.f, nullptr, nullptr, nullptr, 0, hx + 1024, 2048, 0);
    {
      SrlFlashArgs fa;
      fa.Q = q_h; fa.K = k_h; fa.VT = vT_h; fa.O = ctx_h;
      fa.sQb = 1048576; fa.sKb = 1048576; fa.sVb = 1048576; fa.scale = 0.125f * kLog2e;
      hipLaunchKernelGGL(srl_flash, dim3(512), dim3(256), 0, stream, fa);
    }
    runDb1(4096, 1024, 1024, ctx_h, 1024, wt_attn_o, 1024, 1.f, in_attn_bo, h_f, h_f, 1024, hx, 2048, 0);
    runDb1(4096, 1024, 1024, hx, 2048, wt_mq_comp, 1024, 1.f, bcomp, nullptr, nullptr, 0, k_h, 1024, 0);
    {
      SrlFlashArgs fa;
      fa.Q = k_h; fa.K = mak_h; fa.VT = mavT_h; fa.O = ctx_h;
      fa.sQb = 1048576; fa.sKb = 0; fa.sVb = 0; fa.scale = 0.125f * kLog2e;
      hipLaunchKernelGGL(srl_flash, dim3(512), dim3(256), 0, stream, fa);
    }
    runDb1(4096, 1024, 1024, ctx_h, 1024, wt_mattn_o, 1024, 1.f, in_mao_b, h_f, h_f, 1024, hx, 2048, 0);
    {  // ra1 split-K=2 via z: partials in fp32, bias deferred to ln_gelu2
      SrlGemmArgs g{};
      g.nOuts = 1;
      g.out[0] = mkOut(0, nullptr, nullptr, ra1_p0, 1024, nullptr, 0, 0, 0, 4194304);
      runDb(4096, 1024, 1024, hx, 2048, wt_ra1, 2048, 1.f, 2, 0, 1024, 0, 1024, g);
    }
    hipLaunchKernelGGL(srl_ln_gelu2, dim3(4096), dim3(256), 0, stream, ra1_p0, ra1_p1,
                       in_ra_b1, in_ln_s, in_ln_b, u_h);
    runDb1(4096, 1024, 1024, u_h, 1024, wt_ra2, 1024, 1.f, in_ra_b2, h_f, h_f, 1024, hx, 2048, 0);
  }

  hipLaunchKernelGGL(srl_finalize, dim3(5120), dim3(256), 0, stream, h_f, in_conf_w, in_conf_b,
                     (float*)d_out, (float*)d_out + 4194304);
}

// Round 6
// 1149.268 us; speedup vs baseline: 1.1257x; 1.1257x over previous
//
#include <hip/hip_runtime.h>
#include <stdint.h>

typedef _Float16 f16;
typedef __attribute__((ext_vector_type(4))) float floatx4;
typedef __attribute__((ext_vector_type(8))) f16   f16x8;
typedef __attribute__((ext_vector_type(4))) f16   f16x4;

#define GLD_LDS16(gp, lp)                                                                      \
  __builtin_amdgcn_global_load_lds((const __attribute__((address_space(1))) void*)(uintptr_t)(gp), \
                                   (__attribute__((address_space(3))) void*)(uintptr_t)(lp), 16, 0, 0)

// ---------------- generalized f16 MFMA GEMM: C = alpha*A@B^T (+bias)(+resid) ----------------
// Single-buffer global_load_lds K-loop (m97 structure — measured best at these shapes).
// Tile size via template: <128,128> for the big fused projection (896 blocks),
// <64,64> for N<=1024 GEMMs (grid 1024+ blocks -> 4 blocks/CU; grid is the occupancy
// constraint at these shapes, so smaller tiles win despite lower per-wave MFMA density).
struct SrlOut {
  int n0;
  const float* bias;
  const float* resid;
  float* Cf; f16* Cb;
  int ldcf, ldcb, transV;
  long long sCb, sCh;
};
struct SrlGemmArgs {
  const f16* A; const f16* B;
  int M, N, K, lda, ldb;
  long long sAb, sAh, sBb, sBh;
  float alpha;
  int nOuts;
  SrlOut out[4];
};

template<int BM, int BN, int MINW>
__global__ __launch_bounds__(256, MINW) void srl_gemm(SrlGemmArgs g) {
  constexpr int BK = 64;
  constexpr int ACH = BM / 32;                 // A 16B-chunks per thread
  constexpr int BCH = BN / 32;                 // B 16B-chunks per thread
  constexpr int MI  = (BM == 128 && BN == 128) ? 4 : 2;
  constexpr int NI  = (BN == 128) ? 4 : ((BM == 128) ? 4 : 2);
  __shared__ f16 As[BM * BK];
  __shared__ f16 Bs[BN * BK];
  const int tid  = threadIdx.x;
  const int wid  = tid >> 6;
  const int lane = tid & 63;
  const int z  = blockIdx.z, zh = z & 15, zb = z >> 4;

  // XCD-aware swizzle: contiguous m-bands per XCD, n-fastest within
  const int gx = gridDim.x;
  const int NT = gx * gridDim.y;
  const int L  = blockIdx.y * gx + blockIdx.x;
  const int W  = ((NT & 7) == 0) ? ((L & 7) * (NT >> 3) + (L >> 3)) : L;
  const int tn = (W % gx) * BN;
  const int tm = (W / gx) * BM;

  const f16* Ab = g.A + (long long)zb * g.sAb + (long long)zh * g.sAh + (long long)tm * g.lda;
  const f16* Bb = g.B + (long long)zb * g.sBb + (long long)zh * g.sBh + (long long)tn * g.ldb;
  const int maxAr = g.M - 1 - tm;
  const int maxBr = g.N - 1 - tn;

  // staging maps; LDS layout xor-swizzled: elem (row,k) at row*64 + (((k>>3)+row)&7)*8 + (k&7)
  int aR[ACH], aO[ACH];
#pragma unroll
  for (int i = 0; i < ACH; ++i) {
    int e = wid * (BM * 16) + i * 512 + lane * 8;
    int r = e >> 6, s = (e >> 3) & 7;
    aR[i] = r; aO[i] = ((s - r) & 7) * 8;
  }
  int bR[BCH], bO[BCH];
#pragma unroll
  for (int i = 0; i < BCH; ++i) {
    int e = wid * (BN * 16) + i * 512 + lane * 8;
    int r = e >> 6, s = (e >> 3) & 7;
    bR[i] = r; bO[i] = ((s - r) & 7) * 8;
  }
  f16* lA = As + wid * (BM * 16);
  f16* lB = Bs + wid * (BN * 16);

  floatx4 acc[MI][NI];
#pragma unroll
  for (int a = 0; a < MI; ++a)
#pragma unroll
    for (int b = 0; b < NI; ++b) {
      acc[a][b][0] = 0.f; acc[a][b][1] = 0.f; acc[a][b][2] = 0.f; acc[a][b][3] = 0.f;
    }

  // wave tiling: 128x128 -> 2x2 waves of 64x64; 128x64 -> 4x1 waves of 32x64;
  // 64x64 -> 2x2 waves of 32x32
  const int wm = (BM == 128 && BN == 128) ? (wid & 1) * 64
               : (BN == 128)              ? 0
               : (BM == 128)              ? wid * 32
                                          : (wid & 1) * 32;
  const int wn = (BM == 128 && BN == 128) ? (wid >> 1) * 64
               : (BM == 64 && BN == 64)   ? (wid >> 1) * 32
                                          : 0;
  const int lm = lane & 15;
  const int quad = lane >> 4;

  for (int k0 = 0; k0 < g.K; k0 += BK) {
    __syncthreads();
#pragma unroll
    for (int i = 0; i < ACH; ++i) {
      int r = aR[i] <= maxAr ? aR[i] : maxAr;
      GLD_LDS16(Ab + (long long)r * g.lda + (k0 + aO[i]), lA + i * 512);
    }
#pragma unroll
    for (int i = 0; i < BCH; ++i) {
      int r = bR[i] <= maxBr ? bR[i] : maxBr;
      GLD_LDS16(Bb + (long long)r * g.ldb + (k0 + bO[i]), lB + i * 512);
    }
    __syncthreads();
#pragma unroll
    for (int ks = 0; ks < 2; ++ks) {
      f16x8 af[MI], bfr[NI];
#pragma unroll
      for (int mi = 0; mi < MI; ++mi) {
        int row = wm + mi * 16 + lm;
        int sg = ((ks * 4 + quad) + row) & 7;
        af[mi] = *(const f16x8*)(As + row * 64 + sg * 8);
      }
#pragma unroll
      for (int ni = 0; ni < NI; ++ni) {
        int row = wn + ni * 16 + lm;
        int sg = ((ks * 4 + quad) + row) & 7;
        bfr[ni] = *(const f16x8*)(Bs + row * 64 + sg * 8);
      }
#pragma unroll
      for (int mi = 0; mi < MI; ++mi)
#pragma unroll
        for (int ni = 0; ni < NI; ++ni)
          acc[mi][ni] = __builtin_amdgcn_mfma_f32_16x16x32_f16(af[mi], bfr[ni], acc[mi][ni], 0, 0, 0);
    }
  }

  int oi = 0;
  for (int j = 1; j < g.nOuts; ++j)
    if (tn >= g.out[j].n0) oi = j;
  const SrlOut O = g.out[oi];
  const long long zc = (long long)zb * O.sCb + (long long)zh * O.sCh;
#pragma unroll
  for (int mi = 0; mi < MI; ++mi) {
#pragma unroll
    for (int r = 0; r < 4; ++r) {
      int m = tm + wm + mi * 16 + quad * 4 + r;   // C/D: row = quad*4+reg
      if (m >= g.M) continue;
#pragma unroll
      for (int ni = 0; ni < NI; ++ni) {
        int n = tn + wn + ni * 16 + lm;           // C/D: col = lane&15
        if (n >= g.N) continue;
        int nl = n - O.n0;
        float v = acc[mi][ni][r] * g.alpha;
        if (O.bias)  v += O.bias[nl];
        if (O.resid) v += O.resid[(long long)m * O.ldcf + nl];
        if (O.Cf)    O.Cf[zc + (long long)m * O.ldcf + nl] = v;
        if (O.Cb) {
          long long idx = O.transV
              ? ((long long)(m >> 10) * 1048576 + (long long)nl * 1024 + (m & 1023))
              : (zc + (long long)m * O.ldcb + nl);
          O.Cb[idx] = (f16)v;
        }
      }
    }
  }
}

// ---------------- fused flash attention: per-block (b,head,qtile=128), S=1024, d=64 ----------
// S^T = K@Q^T; softmax with fixed shift 0 (scores bounded, softmax shift-invariant);
// scale*log2e folded into Q so exp == v_exp_f32.
struct SrlFlashArgs {
  const f16* Q; const f16* K; const f16* VT; f16* O;
  long long sQb, sKb, sVb;
  float scale;   // includes log2(e)
};

__global__ __launch_bounds__(256, 2) void srl_flash(SrlFlashArgs a) {
  __shared__ f16 Qs[8192];
  __shared__ f16 Ks[8192];
  __shared__ f16 VTs[8192];
  __shared__ f16 Ps[4][4096];
  const int tid = threadIdx.x, wid = tid >> 6, lane = tid & 63;
  const int quad = lane >> 4, c = lane & 15;
  const int L = blockIdx.x;
  const int bh = (L & 7) + ((L >> 6) << 3);
  const int qt = (L >> 3) & 7;
  const int b = bh >> 4, h = bh & 15;
  const f16* Qg = a.Q + (long long)b * a.sQb + (long long)qt * 131072 + h * 64;
  const f16* Kg = a.K + (long long)b * a.sKb + h * 64;
  const f16* Vg = a.VT + (long long)b * a.sVb + (long long)h * 65536;
  f16* Og = a.O + (long long)b * 1048576 + (long long)qt * 131072 + h * 64;

  int rRow[4], rOff[4];
#pragma unroll
  for (int i = 0; i < 4; ++i) {
    int e = wid * 2048 + i * 512 + lane * 8;
    int r = e >> 6, gL = (e >> 3) & 7;
    rRow[i] = r; rOff[i] = ((gL - r) & 7) * 8;
  }
  int vRow[4], vOff[4];
#pragma unroll
  for (int i = 0; i < 4; ++i) {
    int e = wid * 2048 + i * 512 + lane * 8;
    int d = e >> 7, gL = (e >> 3) & 15;
    vRow[i] = d; vOff[i] = ((gL - (d & 7)) & 15) * 8;
  }

#pragma unroll
  for (int i = 0; i < 4; ++i)
    GLD_LDS16(Qg + (long long)rRow[i] * 1024 + rOff[i], Qs + wid * 2048 + i * 512);
  __syncthreads();

  const int wq = wid * 32;
  f16x8 qf[2][2];
#pragma unroll
  for (int nf = 0; nf < 2; ++nf)
#pragma unroll
    for (int ch = 0; ch < 2; ++ch) {
      int row = wq + nf * 16 + c;
      int slot = ((ch * 4 + quad) + row) & 7;
      f16x8 v = *(const f16x8*)(Qs + row * 64 + slot * 8);
      f16 sc = (f16)a.scale;
#pragma unroll
      for (int j = 0; j < 8; ++j) v[j] = v[j] * sc;
      qf[nf][ch] = v;
    }

  float l_s[2] = {0.f, 0.f};
  floatx4 Oa[2][4];
#pragma unroll
  for (int nf = 0; nf < 2; ++nf)
#pragma unroll
    for (int no = 0; no < 4; ++no) {
      Oa[nf][no][0] = 0.f; Oa[nf][no][1] = 0.f; Oa[nf][no][2] = 0.f; Oa[nf][no][3] = 0.f;
    }

  for (int t = 0; t < 8; ++t) {
    __syncthreads();
#pragma unroll
    for (int i = 0; i < 4; ++i)
      GLD_LDS16(Kg + (long long)(t * 128 + rRow[i]) * 1024 + rOff[i], Ks + wid * 2048 + i * 512);
#pragma unroll
    for (int i = 0; i < 4; ++i)
      GLD_LDS16(Vg + (long long)vRow[i] * 1024 + (t * 128 + vOff[i]), VTs + wid * 2048 + i * 512);
    __syncthreads();

    floatx4 sT[2][8];
#pragma unroll
    for (int nf = 0; nf < 2; ++nf)
#pragma unroll
      for (int mf = 0; mf < 8; ++mf) {
        sT[nf][mf][0] = 0.f; sT[nf][mf][1] = 0.f; sT[nf][mf][2] = 0.f; sT[nf][mf][3] = 0.f;
      }
#pragma unroll
    for (int ch = 0; ch < 2; ++ch)
#pragma unroll
      for (int mf = 0; mf < 8; ++mf) {
        int key = mf * 16 + c;
        int slot = ((ch * 4 + quad) + key) & 7;
        f16x8 kf = *(const f16x8*)(Ks + key * 64 + slot * 8);
        sT[0][mf] = __builtin_amdgcn_mfma_f32_16x16x32_f16(kf, qf[0][ch], sT[0][mf], 0, 0, 0);
        sT[1][mf] = __builtin_amdgcn_mfma_f32_16x16x32_f16(kf, qf[1][ch], sT[1][mf], 0, 0, 0);
      }

#pragma unroll
    for (int nf = 0; nf < 2; ++nf) {
      float lt = 0.f;
      const int q = nf * 16 + c;
#pragma unroll
      for (int mf = 0; mf < 8; ++mf) {
        f16x4 pk;
#pragma unroll
        for (int r = 0; r < 4; ++r) {
          float p = __builtin_amdgcn_exp2f(sT[nf][mf][r]);
          lt += p;
          pk[r] = (f16)p;
        }
        int kg = mf * 2 + (quad >> 1), sub = (quad & 1) * 4;
        int slot = (kg + (q & 7)) & 15;
        *(f16x4*)(Ps[wid] + q * 128 + slot * 8 + sub) = pk;
      }
      lt += __shfl_xor(lt, 16);
      lt += __shfl_xor(lt, 32);
      l_s[nf] += lt;
    }
#pragma unroll
    for (int cc = 0; cc < 4; ++cc) {
      f16x8 af[2];
#pragma unroll
      for (int nf = 0; nf < 2; ++nf) {
        int q = nf * 16 + c;
        int slot = ((cc * 4 + quad) + (q & 7)) & 15;
        af[nf] = *(const f16x8*)(Ps[wid] + q * 128 + slot * 8);
      }
#pragma unroll
      for (int no = 0; no < 4; ++no) {
        int d = no * 16 + c;
        int slot = ((cc * 4 + quad) + (d & 7)) & 15;
        f16x8 vf = *(const f16x8*)(VTs + d * 128 + slot * 8);
        Oa[0][no] = __builtin_amdgcn_mfma_f32_16x16x32_f16(af[0], vf, Oa[0][no], 0, 0, 0);
        Oa[1][no] = __builtin_amdgcn_mfma_f32_16x16x32_f16(af[1], vf, Oa[1][no], 0, 0, 0);
      }
    }
  }

#pragma unroll
  for (int nf = 0; nf < 2; ++nf)
#pragma unroll
    for (int r = 0; r < 4; ++r) {
      float li = 1.f / __shfl(l_s[nf], quad * 4 + r);
      int qrow = wq + nf * 16 + quad * 4 + r;
#pragma unroll
      for (int no = 0; no < 4; ++no)
        Qs[qrow * 64 + no * 16 + c] = (f16)(Oa[nf][no][r] * li);
    }
  __syncthreads();
#pragma unroll
  for (int i = 0; i < 4; ++i) {
    int e = wid * 2048 + i * 512 + lane * 8;
    int row = e >> 6, col = e & 63;
    *(f16x8*)(Og + (long long)row * 1024 + col) = *(const f16x8*)(Qs + e);
  }
}

// ---------------- rule softmax: fp32 logits [rows,512] -> f16 probs ----------------
__global__ __launch_bounds__(256) void srl_softmax_rule(const float* logits, f16* probs) {
  __shared__ float red[16];
  const long long row = blockIdx.x;
  const float* p = logits + row * 512;
  const int tid = threadIdx.x;
  float v0 = p[tid], v1 = p[tid + 256];
  float mx = fmaxf(v0, v1);
#pragma unroll
  for (int o = 32; o > 0; o >>= 1) mx = fmaxf(mx, __shfl_down(mx, o));
  const int wid = tid >> 6, lane = tid & 63;
  if (lane == 0) red[wid] = mx;
  __syncthreads();
  if (tid == 0) red[8] = fmaxf(fmaxf(red[0], red[1]), fmaxf(red[2], red[3]));
  __syncthreads();
  mx = red[8];
  float e0 = __expf(v0 - mx), e1 = __expf(v1 - mx);
  float s = e0 + e1;
#pragma unroll
  for (int o = 32; o > 0; o >>= 1) s += __shfl_down(s, o);
  if (lane == 0) red[wid + 4] = s;
  __syncthreads();
  if (tid == 0) red[9] = 1.f / (red[4] + red[5] + red[6] + red[7]);
  __syncthreads();
  const float inv = red[9];
  probs[row * 512 + tid] = (f16)(e0 * inv);
  probs[row * 512 + tid + 256] = (f16)(e1 * inv);
}

// ---------------- LayerNorm + exact GELU: fp32 [rows,1024] -> f16 ----------------
__global__ __launch_bounds__(256) void srl_ln_gelu(const float* x, const float* gam, const float* bet, f16* out) {
  __shared__ float red[16];
  const long long row = blockIdx.x;
  const float* p = x + row * 1024;
  const int tid = threadIdx.x;
  float4 xv = *(const float4*)(p + tid * 4);
  float v[4] = {xv.x, xv.y, xv.z, xv.w};
  float s = v[0] + v[1] + v[2] + v[3];
  float s2 = v[0] * v[0] + v[1] * v[1] + v[2] * v[2] + v[3] * v[3];
#pragma unroll
  for (int o = 32; o > 0; o >>= 1) { s += __shfl_down(s, o); s2 += __shfl_down(s2, o); }
  const int wid = tid >> 6, lane = tid & 63;
  if (lane == 0) { red[wid] = s; red[wid + 4] = s2; }
  __syncthreads();
  if (tid == 0) {
    float ts = red[0] + red[1] + red[2] + red[3];
    float ts2 = red[4] + red[5] + red[6] + red[7];
    float mu = ts * (1.f / 1024.f);
    float var = ts2 * (1.f / 1024.f) - mu * mu;
    red[8] = mu;
    red[9] = rsqrtf(var + 1e-5f);
  }
  __syncthreads();
  const float mu = red[8], rstd = red[9];
  f16x4 o4;
#pragma unroll
  for (int i = 0; i < 4; ++i) {
    int c = tid * 4 + i;
    float t = (v[i] - mu) * rstd * gam[c] + bet[c];
    float ge = 0.5f * t * (1.f + erff(t * 0.70710678118654752f));
    o4[i] = (f16)ge;
  }
  *(f16x4*)(out + row * 1024 + tid * 4) = o4;
}

// ---------------- batched weight convert (+optional transpose) fp32 -> f16 ----------------
struct SrlTcEnt { const float* src; f16* dst; int rows, cols, trans, tileStart; };
struct SrlTcArgs { SrlTcEnt e[16]; };

__global__ __launch_bounds__(256) void srl_convert_weights(SrlTcArgs a) {
  __shared__ float t[32][33];
  const int bt = blockIdx.x;
  int ei = 0;
#pragma unroll
  for (int j = 1; j < 16; ++j)
    if (bt >= a.e[j].tileStart) ei = j;
  SrlTcEnt E = a.e[ei];
  const int lt = bt - E.tileStart;
  const int tcols = E.cols >> 5;
  const int tr = lt / tcols;
  const int tc = lt - tr * tcols;
  const int r = threadIdx.x >> 5;
  const int c = threadIdx.x & 31;
  if (!E.trans) {
#pragma unroll
    for (int p = 0; p < 4; ++p) {
      long long rr = tr * 32 + r + p * 8;
      long long idx = rr * E.cols + tc * 32 + c;
      E.dst[idx] = (f16)E.src[idx];
    }
  } else {
#pragma unroll
    for (int p = 0; p < 4; ++p)
      t[r + p * 8][c] = E.src[(long long)(tr * 32 + r + p * 8) * E.cols + tc * 32 + c];
    __syncthreads();
#pragma unroll
    for (int p = 0; p < 4; ++p)
      E.dst[(long long)(tc * 32 + r + p * 8) * E.rows + tr * 32 + c] = (f16)t[c][r + p * 8];
  }
}

// ---------------- fused bias prep ----------------
__global__ __launch_bounds__(256) void srl_prep_bias(const float* rsel_b, const float* bq,
                                                     const float* bk, const float* bv,
                                                     const float* bmq, const float* maq_w,
                                                     const float* bmaq,
                                                     float* bias_qkvr, float* bcomp) {
  int i = blockIdx.x * 256 + threadIdx.x;
  if (i < 3584) {
    float v;
    if (i < 512) v = rsel_b[i];
    else if (i < 1536) v = bq[i - 512];
    else if (i < 2560) v = bk[i - 1536];
    else v = bv[i - 2560];
    bias_qkvr[i] = v;
  } else if (i < 3584 + 1024) {
    int m = i - 3584;
    float s = bmaq[m];
    for (int t = 0; t < 1024; ++t) s += bmq[t] * maq_w[(long long)t * 1024 + m];
    bcomp[m] = s;
  }
}

// ---------------- h init / finalize ----------------
__global__ __launch_bounds__(256) void srl_h_init(const float* hidden, float* hf, f16* hx) {
  long long base = ((long long)blockIdx.x * 256 + threadIdx.x) * 4;
  float4 v = *(const float4*)(hidden + base);
  *(float4*)(hf + base) = v;
  long long row = base >> 10;
  int col = (int)(base & 1023);
  f16x4 b;
  b[0] = (f16)v.x; b[1] = (f16)v.y; b[2] = (f16)v.z; b[3] = (f16)v.w;
  *(f16x4*)(hx + row * 2048 + col) = b;
}

__global__ __launch_bounds__(256) void srl_finalize(const float* hf, const float* w, const float* b,
                                                    float* out, float* conf) {
  const int bid = blockIdx.x;
  if (bid < 4096) {
    long long base = ((long long)bid * 256 + threadIdx.x) * 4;
    *(float4*)(out + base) = *(const float4*)(hf + base);
  } else {
    const int row = (bid - 4096) * 4 + (threadIdx.x >> 6);
    const int lane = threadIdx.x & 63;
    const float* p = hf + (long long)row * 1024;
    float s = 0.f;
    for (int j = lane; j < 1024; j += 64) s += p[j] * w[j];
#pragma unroll
    for (int o = 32; o > 0; o >>= 1) s += __shfl_down(s, o);
    if (lane == 0) conf[row] = 1.f / (1.f + __expf(-(s + b[0])));
  }
}

// =====================================================================================
extern "C" void kernel_launch(void* const* d_in, const int* in_sizes, int n_in,
                              void* d_out, int out_size, void* d_ws, size_t ws_size,
                              hipStream_t stream) {
  (void)in_sizes; (void)n_in; (void)out_size; (void)ws_size;
  const float* in_hidden   = (const float*)d_in[0];
  const float* in_rule_emb = (const float*)d_in[1];
  const float* in_rsel_w   = (const float*)d_in[2];
  const float* in_rsel_b   = (const float*)d_in[3];
  const float* in_attn_wq  = (const float*)d_in[4];
  const float* in_attn_bq  = (const float*)d_in[5];
  const float* in_attn_wk  = (const float*)d_in[6];
  const float* in_attn_bk  = (const float*)d_in[7];
  const float* in_attn_wv  = (const float*)d_in[8];
  const float* in_attn_bv  = (const float*)d_in[9];
  const float* in_attn_wo  = (const float*)d_in[10];
  const float* in_attn_bo  = (const float*)d_in[11];
  const float* in_memory   = (const float*)d_in[12];
  const float* in_mq_w     = (const float*)d_in[13];
  const float* in_mq_b     = (const float*)d_in[14];
  const float* in_mk_w     = (const float*)d_in[15];
  const float* in_mk_b     = (const float*)d_in[16];
  const float* in_mv_w     = (const float*)d_in[17];
  const float* in_mv_b     = (const float*)d_in[18];
  const float* in_maq_w    = (const float*)d_in[19];
  const float* in_maq_b    = (const float*)d_in[20];
  const float* in_mak_w    = (const float*)d_in[21];
  const float* in_mak_b    = (const float*)d_in[22];
  const float* in_mav_w    = (const float*)d_in[23];
  const float* in_mav_b    = (const float*)d_in[24];
  const float* in_mao_w    = (const float*)d_in[25];
  const float* in_mao_b    = (const float*)d_in[26];
  const float* in_ra_w1    = (const float*)d_in[27];
  const float* in_ra_b1    = (const float*)d_in[28];
  const float* in_ln_s     = (const float*)d_in[29];
  const float* in_ln_b     = (const float*)d_in[30];
  const float* in_ra_w2    = (const float*)d_in[31];
  const float* in_ra_b2    = (const float*)d_in[32];
  const float* in_conf_w   = (const float*)d_in[33];
  const float* in_conf_b   = (const float*)d_in[34];

  char* ws = (char*)d_ws;
  size_t off = 0;
  auto alloc = [&](size_t bytes) -> void* {
    void* p = ws + off;
    off = (off + bytes + 255) & ~(size_t)255;
    return p;
  };
  f16* wt_qkvr    = (f16*)alloc(3584 * 1024 * 2);
  float* bias_qkvr= (float*)alloc(3584 * 4);
  f16* wt_attn_o  = (f16*)alloc(1048576 * 2);
  f16* wt_mq_comp = (f16*)alloc(1048576 * 2);
  float* bcomp    = (float*)alloc(1024 * 4);
  f16* wt_mattn_o = (f16*)alloc(1048576 * 2);
  f16* wt_ra1     = (f16*)alloc(2097152 * 2);
  f16* wt_ra2     = (f16*)alloc(1048576 * 2);
  f16* wt_remb    = (f16*)alloc(524288 * 2);
  f16* wt_mem_kv  = (f16*)alloc(2097152 * 2);
  f16* wt_mattn_k = (f16*)alloc(1048576 * 2);
  f16* wt_mattn_v = (f16*)alloc(1048576 * 2);
  f16* mem_h      = (f16*)alloc(1048576 * 2);
  f16* mk_h       = (f16*)alloc(1048576 * 2);
  f16* mv_h       = (f16*)alloc(1048576 * 2);
  f16* mak_h      = (f16*)alloc(1048576 * 2);
  f16* mavT_h     = (f16*)alloc(1048576 * 2);
  float* h_f      = (float*)alloc(4194304 * 4);
  f16* hx         = (f16*)alloc(8388608 * 2);
  f16* q_h        = (f16*)alloc(4194304 * 2);
  f16* k_h        = (f16*)alloc(4194304 * 2);
  f16* vT_h       = (f16*)alloc(4194304 * 2);
  f16* ctx_h      = (f16*)alloc(4194304 * 2);
  f16* u_h        = (f16*)alloc(4194304 * 2);
  char* arena     = (char*)alloc(16777216);
  float* logits_f = (float*)arena;
  f16* probs_h    = (f16*)(arena + 8388608);
  float* ra1_f    = (float*)arena;
  f16* mqw_nt     = (f16*)arena;
  f16* wmaq_t     = (f16*)(arena + 2097152);

  auto mkOut = [](int n0, const float* bias, const float* resid, float* Cf, int ldcf,
                  f16* Cb, int ldcb, int transV, long long sCb, long long sCh) {
    SrlOut o;
    o.n0 = n0; o.bias = bias; o.resid = resid; o.Cf = Cf; o.Cb = Cb;
    o.ldcf = ldcf; o.ldcb = ldcb; o.transV = transV; o.sCb = sCb; o.sCh = sCh;
    return o;
  };
  // big fused projection kernel: 128x128 tiles
  auto runBig = [&](int M, int N, int K, const f16* A, int lda, const f16* B, int ldb,
                    float alpha, SrlGemmArgs g) {
    g.A = A; g.B = B; g.M = M; g.N = N; g.K = K; g.lda = lda; g.ldb = ldb;
    g.sAb = 0; g.sAh = 0; g.sBb = 0; g.sBh = 0; g.alpha = alpha;
    dim3 grid((N + 127) / 128, (M + 127) / 128, 1);
    hipLaunchKernelGGL((srl_gemm<128, 128, 2>), grid, dim3(256), 0, stream, g);
  };
  // 64x64 tile kernel for N<=1024 GEMMs (grid>=1024 blocks -> 4 blocks/CU)
  auto runSm1 = [&](int M, int N, int K, const f16* A, int lda, const f16* B, int ldb,
                    float alpha, const float* bias, const float* resid, float* Cf, int ldcf,
                    f16* Cb, int ldcb, int transV) {
    SrlGemmArgs g{};
    g.nOuts = 1;
    g.out[0] = mkOut(0, bias, resid, Cf, ldcf, Cb, ldcb, transV, 0, 0);
    g.A = A; g.B = B; g.M = M; g.N = N; g.K = K; g.lda = lda; g.ldb = ldb;
    g.sAb = 0; g.sAh = 0; g.sBb = 0; g.sBh = 0; g.alpha = alpha;
    dim3 grid((N + 63) / 64, (M + 63) / 64, 1);
    hipLaunchKernelGGL((srl_gemm<64, 64, 4>), grid, dim3(256), 0, stream, g);
  };
  auto runSm = [&](int M, int N, int K, const f16* A, int lda, const f16* B, int ldb,
                   float alpha, SrlGemmArgs g) {
    g.A = A; g.B = B; g.M = M; g.N = N; g.K = K; g.lda = lda; g.ldb = ldb;
    g.sAb = 0; g.sAh = 0; g.sBb = 0; g.sBh = 0; g.alpha = alpha;
    dim3 grid((N + 63) / 64, (M + 63) / 64, 1);
    hipLaunchKernelGGL((srl_gemm<64, 64, 4>), grid, dim3(256), 0, stream, g);
  };

  // ---- one-time weight convert/transpose ----
  SrlTcArgs tc;
  int ts = 0;
  auto setent = [&](int i, const float* s, f16* d, int rows, int cols, int trans) {
    tc.e[i].src = s; tc.e[i].dst = d; tc.e[i].rows = rows; tc.e[i].cols = cols;
    tc.e[i].trans = trans; tc.e[i].tileStart = ts;
    ts += (rows / 32) * (cols / 32);
  };
  setent(0,  in_attn_wq, wt_qkvr + 512 * 1024, 1024, 1024, 1);
  setent(1,  in_attn_wk, wt_qkvr + 1536 * 1024, 1024, 1024, 1);
  setent(2,  in_attn_wv, wt_qkvr + 2560 * 1024, 1024, 1024, 1);
  setent(3,  in_rsel_w,  wt_qkvr, 1024, 512, 1);
  setent(4,  in_attn_wo, wt_attn_o, 1024, 1024, 1);
  setent(5,  in_mq_w,    mqw_nt, 1024, 1024, 0);
  setent(6,  in_maq_w,   wmaq_t, 1024, 1024, 1);
  setent(7,  in_mak_w,   wt_mattn_k, 1024, 1024, 1);
  setent(8,  in_mav_w,   wt_mattn_v, 1024, 1024, 1);
  setent(9,  in_mk_w,    wt_mem_kv, 1024, 1024, 1);
  setent(10, in_mv_w,    wt_mem_kv + 1048576, 1024, 1024, 1);
  setent(11, in_mao_w,   wt_mattn_o, 1024, 1024, 1);
  setent(12, in_ra_w1,   wt_ra1, 2048, 1024, 1);
  setent(13, in_ra_w2,   wt_ra2, 1024, 1024, 1);
  setent(14, in_rule_emb, wt_remb, 512, 1024, 1);
  setent(15, in_memory,  mem_h, 1024, 1024, 0);
  hipLaunchKernelGGL(srl_convert_weights, dim3(ts), dim3(256), 0, stream, tc);
  hipLaunchKernelGGL(srl_prep_bias, dim3(18), dim3(256), 0, stream,
                     in_rsel_b, in_attn_bq, in_attn_bk, in_attn_bv,
                     in_mq_b, in_maq_w, in_maq_b, bias_qkvr, bcomp);
  hipLaunchKernelGGL(srl_h_init, dim3(4096), dim3(256), 0, stream, in_hidden, h_f, hx);

  // ---- preamble GEMMs ----
  {
    SrlGemmArgs g{};
    g.nOuts = 2;
    g.out[0] = mkOut(0, in_mk_b, nullptr, nullptr, 0, mk_h, 1024, 0, 0, 0);
    g.out[1] = mkOut(1024, in_mv_b, nullptr, nullptr, 0, mv_h, 1024, 0, 0, 0);
    runSm(1024, 2048, 1024, mem_h, 1024, wt_mem_kv, 1024, 1.f, g);
  }
  runSm1(1024, 1024, 1024, mk_h, 1024, wt_mattn_k, 1024, 1.f, in_mak_b, nullptr, nullptr, 0, mak_h, 1024, 0);
  runSm1(1024, 1024, 1024, mv_h, 1024, wt_mattn_v, 1024, 1.f, in_mav_b, nullptr, nullptr, 0, mavT_h, 0, 1);
  runSm1(1024, 1024, 1024, wmaq_t, 1024, mqw_nt, 1024, 1.f, nullptr, nullptr, nullptr, 0, wt_mq_comp, 1024, 0);

  const float kLog2e = 1.4426950408889634f;
  for (int step = 0; step < 3; ++step) {
    {  // fused rule-logits + Q + K + V projection: 128x128 tiles, 896 blocks
      SrlGemmArgs g{};
      g.nOuts = 4;
      g.out[0] = mkOut(0,    bias_qkvr,        nullptr, logits_f, 512, nullptr, 0, 0, 0, 0);
      g.out[1] = mkOut(512,  bias_qkvr + 512,  nullptr, nullptr, 0, q_h, 1024, 0, 0, 0);
      g.out[2] = mkOut(1536, bias_qkvr + 1536, nullptr, nullptr, 0, k_h, 1024, 0, 0, 0);
      g.out[3] = mkOut(2560, bias_qkvr + 2560, nullptr, nullptr, 0, vT_h, 0, 1, 0, 0);
      runBig(4096, 3584, 1024, hx, 2048, wt_qkvr, 1024, 1.f, g);
    }
    hipLaunchKernelGGL(srl_softmax_rule, dim3(4096), dim3(256), 0, stream, logits_f, probs_h);
    runSm1(4096, 1024, 512, probs_h, 512, wt_remb, 512, 1.f, nullptr, nullptr, nullptr, 0, hx + 1024, 2048, 0);
    {
      SrlFlashArgs fa;
      fa.Q = q_h; fa.K = k_h; fa.VT = vT_h; fa.O = ctx_h;
      fa.sQb = 1048576; fa.sKb = 1048576; fa.sVb = 1048576; fa.scale = 0.125f * kLog2e;
      hipLaunchKernelGGL(srl_flash, dim3(512), dim3(256), 0, stream, fa);
    }
    runSm1(4096, 1024, 1024, ctx_h, 1024, wt_attn_o, 1024, 1.f, in_attn_bo, h_f, h_f, 1024, hx, 2048, 0);
    runSm1(4096, 1024, 1024, hx, 2048, wt_mq_comp, 1024, 1.f, bcomp, nullptr, nullptr, 0, k_h, 1024, 0);
    {
      SrlFlashArgs fa;
      fa.Q = k_h; fa.K = mak_h; fa.VT = mavT_h; fa.O = ctx_h;
      fa.sQb = 1048576; fa.sKb = 0; fa.sVb = 0; fa.scale = 0.125f * kLog2e;
      hipLaunchKernelGGL(srl_flash, dim3(512), dim3(256), 0, stream, fa);
    }
    runSm1(4096, 1024, 1024, ctx_h, 1024, wt_mattn_o, 1024, 1.f, in_mao_b, h_f, h_f, 1024, hx, 2048, 0);
    runSm1(4096, 1024, 2048, hx, 2048, wt_ra1, 2048, 1.f, in_ra_b1, nullptr, ra1_f, 1024, nullptr, 0, 0);
    hipLaunchKernelGGL(srl_ln_gelu, dim3(4096), dim3(256), 0, stream, ra1_f, in_ln_s, in_ln_b, u_h);
    runSm1(4096, 1024, 1024, u_h, 1024, wt_ra2, 1024, 1.f, in_ra_b2, h_f, h_f, 1024, hx, 2048, 0);
  }

  hipLaunchKernelGGL(srl_finalize, dim3(5120), dim3(256), 0, stream, h_f, in_conf_w, in_conf_b,
                     (float*)d_out, (float*)d_out + 4194304);
}